// Round 5
// baseline (91.427 us; speedup 1.0000x reference)
//
#include <hip/hip_runtime.h>
#include <math.h>

#define NA   1024     // num agents
#define HD   128      // hidden dim
#define GG   16       // G*G cells
#define PD   128      // pool (output) dim
#define FAN  2048     // GG*HD
#define CAP  128      // max neighbors per (agent, cell); mean ~17, CAP=128 is +14 sigma

typedef float  f32x4  __attribute__((ext_vector_type(4)));
typedef short  bf16x8 __attribute__((ext_vector_type(8)));
typedef unsigned short ushort_t;
typedef unsigned int   uint_t;

// RNE float -> bf16 (matches hardware convert for finite values)
static __device__ __forceinline__ ushort_t f2bf(float f) {
    uint_t u = __float_as_uint(f);
    u += 0x7fffu + ((u >> 16) & 1u);
    return (ushort_t)(u >> 16);
}

// ---------------- Kernel 1: social pooling (bf16 out) + W->bf16 convert ----
// one block per agent, 256 threads (4 waves). Wave w owns cells 4w..4w+3;
// running max lives in registers (float2 per lane = 2 of 128 h-values).
// L2-BW-bound: ~143 MB of hidden re-reads / 34.5 TB/s ~= 4.1 us floor.
__global__ __launch_bounds__(256) void pool_kernel(
    const float* __restrict__ pos,
    const float* __restrict__ hidden,
    const float* __restrict__ W,
    ushort_t*    __restrict__ Wbf,     // [PD][FAN] bf16
    uint_t*      __restrict__ pooledu) // [NA][FAN/2] packed bf16x2
{
    __shared__ int lists[GG][CAP];   // per-cell compacted neighbor indices, 8 KB
    __shared__ int cnt[GG];

    const int i = blockIdx.x;
    const int t = threadIdx.x;

    // W -> bf16 conversion, spread over the whole grid (1024*256 == PD*FAN)
    {
        const int e = i * 256 + t;
        Wbf[e] = f2bf(W[e]);
    }

    if (t < GG) cnt[t] = 0;
    __syncthreads();

    const float px = pos[2 * i], py = pos[2 * i + 1];

    // Pass A: classify every j, append to its cell's list.
    // NaN/inf positions propagate into dx/dy and fail the <= compares,
    // matching the reference's finite-pos masking.
    for (int j = t; j < NA; j += 256) {
        float dx = pos[2 * j]     - px;
        float dy = pos[2 * j + 1] - py;
        bool inbox = (fabsf(dx) <= 1.0f) && (fabsf(dy) <= 1.0f) && (j != i);
        if (inbox) {
            int gx = min(max((int)floorf((dx + 1.0f) * 2.0f), 0), 3);
            int gy = min(max((int)floorf((dy + 1.0f) * 2.0f), 0), 3);
            int c  = gx * 4 + gy;
            int slot = atomicAdd(&cnt[c], 1);
            if (slot < CAP) lists[c][slot] = j;
        }
    }
    __syncthreads();

    // Pass B: register-resident max, uniform inner loop, 4 loads in flight.
    const int w = t >> 6, lane = t & 63;
    const float2* __restrict__ hid2 = (const float2*)hidden;   // [NA][64]
    uint_t* outrow = pooledu + (size_t)i * (FAN / 2);

    #pragma unroll
    for (int q = 0; q < 4; ++q) {
        const int c = w * 4 + q;
        const int n = min(cnt[c], CAP);
        const int* lst = lists[c];
        float2 r = make_float2(-INFINITY, -INFINITY);
        int k = 0;
        for (; k + 4 <= n; k += 4) {
            int j0 = lst[k], j1 = lst[k + 1], j2 = lst[k + 2], j3 = lst[k + 3];
            float2 v0 = hid2[j0 * 64 + lane];
            float2 v1 = hid2[j1 * 64 + lane];
            float2 v2 = hid2[j2 * 64 + lane];
            float2 v3 = hid2[j3 * 64 + lane];
            r.x = fmaxf(fmaxf(fmaxf(v0.x, v1.x), fmaxf(v2.x, v3.x)), r.x);
            r.y = fmaxf(fmaxf(fmaxf(v0.y, v1.y), fmaxf(v2.y, v3.y)), r.y);
        }
        for (; k < n; ++k) {
            float2 v = hid2[lst[k] * 64 + lane];
            r.x = fmaxf(r.x, v.x);
            r.y = fmaxf(r.y, v.y);
        }
        if (n == 0) { r.x = 0.0f; r.y = 0.0f; }   // empty cell -> zeros (cnt>0 semantics)
        // pack 2 bf16 (h = 2*lane low, 2*lane+1 high)
        outrow[c * 64 + lane] = (uint_t)f2bf(r.x) | ((uint_t)f2bf(r.y) << 16);
    }
}

// ------- Kernel 2: bf16 MFMA GEMM, zero-LDS, full-K, fused bias+relu ------
// out[m][p] = relu( sum_k pooled[m][k] * W[p][k] + bias[p] )
// grid (64 m-tiles, 2 n-halves) x 256 thr (4 waves); wave w: 16x16 tile at
// n0 = nh*64 + w*16, full K=2048 with two parity accumulators for ILP.
// A/B frag (16x16x32): lane l -> row (l&15), k = (l>>4)*8 + j.
// D layout (m89-verified): col(n) = lane&15, row(m) = (lane>>4)*4 + reg.
__global__ __launch_bounds__(256) void gemm_kernel(
    const ushort_t* __restrict__ Abf,  // pooled [NA][FAN] bf16
    const ushort_t* __restrict__ Wbf,  // [PD][FAN] bf16
    const float*    __restrict__ bias, // [PD]
    float* __restrict__ out)           // [NA][PD]
{
    const int mt = blockIdx.x;    // 0..63
    const int nh = blockIdx.y;    // 0..1
    const int w  = threadIdx.x >> 6;
    const int l  = threadIdx.x & 63;
    const int m0 = mt * 16;
    const int n0 = nh * 64 + w * 16;

    const int lm = l & 15;          // row within the 16 (m for A, n for B)
    const int kg = (l >> 4) * 8;    // k-offset within the 32-wide step

    const ushort_t* aptr = Abf + (size_t)(m0 + lm) * FAN + kg;
    const ushort_t* bptr = Wbf + (size_t)(n0 + lm) * FAN + kg;

    f32x4 acc0 = {0.f, 0.f, 0.f, 0.f};
    f32x4 acc1 = {0.f, 0.f, 0.f, 0.f};

    #pragma unroll 8
    for (int kt = 0; kt < FAN; kt += 64) {
        bf16x8 a0 = *(const bf16x8*)(aptr + kt);
        bf16x8 b0 = *(const bf16x8*)(bptr + kt);
        bf16x8 a1 = *(const bf16x8*)(aptr + kt + 32);
        bf16x8 b1 = *(const bf16x8*)(bptr + kt + 32);
        acc0 = __builtin_amdgcn_mfma_f32_16x16x32_bf16(a0, b0, acc0, 0, 0, 0);
        acc1 = __builtin_amdgcn_mfma_f32_16x16x32_bf16(a1, b1, acc1, 0, 0, 0);
    }

    const float bv = bias[n0 + lm];
    const int row0 = (l >> 4) * 4;
    float* p0 = out + (size_t)(m0 + row0) * PD + n0 + lm;
    #pragma unroll
    for (int r = 0; r < 4; ++r)
        p0[r * PD] = fmaxf(acc0[r] + acc1[r] + bv, 0.0f);
}

extern "C" void kernel_launch(void* const* d_in, const int* in_sizes, int n_in,
                              void* d_out, int out_size, void* d_ws, size_t ws_size,
                              hipStream_t stream)
{
    const float* pos    = (const float*)d_in[0];
    const float* hidden = (const float*)d_in[1];
    const float* W      = (const float*)d_in[2];
    const float* b      = (const float*)d_in[3];
    float* out = (float*)d_out;

    ushort_t* Wbf    = (ushort_t*)d_ws;             // 512 KB
    ushort_t* pooled = Wbf + (size_t)PD * FAN;      // 4 MB bf16

    pool_kernel<<<NA, 256, 0, stream>>>(pos, hidden, W, Wbf, (uint_t*)pooled);
    gemm_kernel<<<dim3(NA / 16, 2), 256, 0, stream>>>(pooled, Wbf, b, out);
}

// Round 7
// 84.606 us; speedup vs baseline: 1.0806x; 1.0806x over previous
//
#include <hip/hip_runtime.h>
#include <math.h>

#define NA   1024     // num agents
#define HD   128      // hidden dim
#define GG   16       // G*G cells
#define PD   128      // pool (output) dim
#define FAN  2048     // GG*HD
#define CAP  128      // max neighbors per (agent, cell); mean ~17, CAP=128 is +14 sigma

typedef float  f32x4  __attribute__((ext_vector_type(4)));
typedef short  bf16x8 __attribute__((ext_vector_type(8)));
typedef unsigned short ushort_t;
typedef unsigned int   uint_t;

// RNE float -> bf16 (matches hardware convert for finite values)
static __device__ __forceinline__ ushort_t f2bf(float f) {
    uint_t u = __float_as_uint(f);
    u += 0x7fffu + ((u >> 16) & 1u);
    return (ushort_t)(u >> 16);
}

// ---------------- Kernel 1: social pooling (bf16 out) + W->bf16 convert ----
// one block per agent, 256 threads (4 waves). Wave w owns cells 4w..4w+3;
// running max lives in registers (float2 per lane = 2 of 128 h-values).
// L2-BW-bound: ~143 MB of hidden re-reads / 34.5 TB/s ~= 4.1 us floor.
__global__ __launch_bounds__(256) void pool_kernel(
    const float* __restrict__ pos,
    const float* __restrict__ hidden,
    const float* __restrict__ W,
    ushort_t*    __restrict__ Wbf,     // [PD][FAN] bf16
    uint_t*      __restrict__ pooledu) // [NA][FAN/2] packed bf16x2
{
    __shared__ int lists[GG][CAP];   // per-cell compacted neighbor indices, 8 KB
    __shared__ int cnt[GG];

    const int i = blockIdx.x;
    const int t = threadIdx.x;

    // W -> bf16 conversion, spread over the whole grid (1024*256 == PD*FAN)
    {
        const int e = i * 256 + t;
        Wbf[e] = f2bf(W[e]);
    }

    if (t < GG) cnt[t] = 0;
    __syncthreads();

    const float px = pos[2 * i], py = pos[2 * i + 1];

    // Pass A: classify every j, append to its cell's list.
    // NaN/inf positions propagate into dx/dy and fail the <= compares,
    // matching the reference's finite-pos masking.
    for (int j = t; j < NA; j += 256) {
        float dx = pos[2 * j]     - px;
        float dy = pos[2 * j + 1] - py;
        bool inbox = (fabsf(dx) <= 1.0f) && (fabsf(dy) <= 1.0f) && (j != i);
        if (inbox) {
            int gx = min(max((int)floorf((dx + 1.0f) * 2.0f), 0), 3);
            int gy = min(max((int)floorf((dy + 1.0f) * 2.0f), 0), 3);
            int c  = gx * 4 + gy;
            int slot = atomicAdd(&cnt[c], 1);
            if (slot < CAP) lists[c][slot] = j;
        }
    }
    __syncthreads();

    // Pass B: register-resident max, uniform inner loop, 4 loads in flight.
    const int w = t >> 6, lane = t & 63;
    const float2* __restrict__ hid2 = (const float2*)hidden;   // [NA][64]
    uint_t* outrow = pooledu + (size_t)i * (FAN / 2);

    #pragma unroll
    for (int q = 0; q < 4; ++q) {
        const int c = w * 4 + q;
        const int n = min(cnt[c], CAP);
        const int* lst = lists[c];
        float2 r = make_float2(-INFINITY, -INFINITY);
        int k = 0;
        for (; k + 4 <= n; k += 4) {
            int j0 = lst[k], j1 = lst[k + 1], j2 = lst[k + 2], j3 = lst[k + 3];
            float2 v0 = hid2[j0 * 64 + lane];
            float2 v1 = hid2[j1 * 64 + lane];
            float2 v2 = hid2[j2 * 64 + lane];
            float2 v3 = hid2[j3 * 64 + lane];
            r.x = fmaxf(fmaxf(fmaxf(v0.x, v1.x), fmaxf(v2.x, v3.x)), r.x);
            r.y = fmaxf(fmaxf(fmaxf(v0.y, v1.y), fmaxf(v2.y, v3.y)), r.y);
        }
        for (; k < n; ++k) {
            float2 v = hid2[lst[k] * 64 + lane];
            r.x = fmaxf(r.x, v.x);
            r.y = fmaxf(r.y, v.y);
        }
        if (n == 0) { r.x = 0.0f; r.y = 0.0f; }   // empty cell -> zeros (cnt>0 semantics)
        // pack 2 bf16 (h = 2*lane low, 2*lane+1 high)
        outrow[c * 64 + lane] = (uint_t)f2bf(r.x) | ((uint_t)f2bf(r.y) << 16);
    }
}

// --- Kernel 2: bf16 MFMA GEMM, zero-LDS staging, wave-split-K, fused ------
// out[m][p] = relu( sum_k pooled[m][k] * W[p][k] + bias[p] )
// grid (64 m-tiles, 8 n-tiles) = 512 blocks (2/CU, 8 waves/CU for TLP).
// Block owns one 16x16 output tile; wave w computes K-chunk [w*512,(w+1)*512)
// with two parity accumulators, then 4KB LDS cross-wave reduce + bias + relu.
// A/B frag (16x16x32): lane l -> row (l&15), k = (l>>4)*8 + j.
// D layout (m89-verified): col(n) = lane&15, row(m) = (lane>>4)*4 + reg.
__global__ __launch_bounds__(256) void gemm_kernel(
    const ushort_t* __restrict__ Abf,  // pooled [NA][FAN] bf16
    const ushort_t* __restrict__ Wbf,  // [PD][FAN] bf16
    const float*    __restrict__ bias, // [PD]
    float* __restrict__ out)           // [NA][PD]
{
    __shared__ float red[4][256];      // per-wave 16x16 partial tiles

    const int mt = blockIdx.x;    // 0..63
    const int nt = blockIdx.y;    // 0..7
    const int w  = threadIdx.x >> 6;
    const int l  = threadIdx.x & 63;
    const int m0 = mt * 16;
    const int n0 = nt * 16;

    const int lm = l & 15;          // row within the 16 (m for A, n for B)
    const int kg = (l >> 4) * 8;    // k-offset within the 32-wide step
    const int k0 = w * (FAN / 4);   // this wave's K chunk

    const ushort_t* aptr = Abf + (size_t)(m0 + lm) * FAN + k0 + kg;
    const ushort_t* bptr = Wbf + (size_t)(n0 + lm) * FAN + k0 + kg;

    f32x4 acc0 = {0.f, 0.f, 0.f, 0.f};
    f32x4 acc1 = {0.f, 0.f, 0.f, 0.f};

    #pragma unroll
    for (int kt = 0; kt < FAN / 4; kt += 64) {
        bf16x8 a0 = *(const bf16x8*)(aptr + kt);
        bf16x8 b0 = *(const bf16x8*)(bptr + kt);
        bf16x8 a1 = *(const bf16x8*)(aptr + kt + 32);
        bf16x8 b1 = *(const bf16x8*)(bptr + kt + 32);
        acc0 = __builtin_amdgcn_mfma_f32_16x16x32_bf16(a0, b0, acc0, 0, 0, 0);
        acc1 = __builtin_amdgcn_mfma_f32_16x16x32_bf16(a1, b1, acc1, 0, 0, 0);
    }

    const int row0 = (l >> 4) * 4;
    #pragma unroll
    for (int r = 0; r < 4; ++r)
        red[w][(row0 + r) * 16 + lm] = acc0[r] + acc1[r];
    __syncthreads();

    const int t = threadIdx.x;      // t>>4 = m within tile, t&15 = n within tile
    float s = red[0][t] + red[1][t] + red[2][t] + red[3][t] + bias[n0 + (t & 15)];
    out[(size_t)(m0 + (t >> 4)) * PD + n0 + (t & 15)] = fmaxf(s, 0.0f);
}

extern "C" void kernel_launch(void* const* d_in, const int* in_sizes, int n_in,
                              void* d_out, int out_size, void* d_ws, size_t ws_size,
                              hipStream_t stream)
{
    const float* pos    = (const float*)d_in[0];
    const float* hidden = (const float*)d_in[1];
    const float* W      = (const float*)d_in[2];
    const float* b      = (const float*)d_in[3];
    float* out = (float*)d_out;

    ushort_t* Wbf    = (ushort_t*)d_ws;             // 512 KB
    ushort_t* pooled = Wbf + (size_t)PD * FAN;      // 4 MB bf16

    pool_kernel<<<NA, 256, 0, stream>>>(pos, hidden, W, Wbf, (uint_t*)pooled);
    gemm_kernel<<<dim3(NA / 16, 8), 256, 0, stream>>>(pooled, Wbf, b, out);
}